// Round 3
// 10735.879 us; speedup vs baseline: 1.0727x; 1.0727x over previous
//
#include <hip/hip_runtime.h>

// ---------------------------------------------------------------------------
// 2-layer LSTM (S=4096, B=64, I=14, H=256) + ReLU + FC(256->1), eval mode.
// R8: tag-in-data protocol on PROVEN agent-scope transport.
//  - R6/R7 FAILURE: sc0-only asm transport never became visible (stale-L1
//    spin or cross-XCD L2 dirtiness) -> tags never arrived -> budget bail ->
//    garbage. R5's __hip_atomic agent-scope transport is the proven path.
//  - R8 keeps R6's structural wins (no notify counters, no vmcnt(0) publish
//    ack, consumers spin directly on 64-bit tagged data words, L1's 7 gather
//    loads in ONE batch) but carries ALL inter-WG traffic with `sc0 sc1`
//    (bypass L1 + non-coherent L2; coherence point = Infinity Cache).
//  - Static 32-WG role assignment (R5 decode); no XCD claim protocol.
//  - Spin budget 1<<24: never triggers normally; converts genuine protocol
//    failure into garbage + clean test failure instead of a hang.
// ---------------------------------------------------------------------------

#define S_LEN 4096
#define BATCH 64
#define IN_DIM 14
#define HID 256
#define GATES 1024
#define K0 288        // layer0 K (h256 | x14 | pad18)
#define LDA0 296      // LDS A row stride (f16), layer0
#define K1 512        // layer1 K (h1 | hs0)
#define LDA1 520      // LDS A row stride (f16), layer1
#define GST 260       // gate LDS row stride (f32): 2-way only (free)

typedef _Float16 half8 __attribute__((ext_vector_type(8)));
typedef float f32x4 __attribute__((ext_vector_type(4)));
typedef unsigned long long u64;
typedef unsigned int u32;

__device__ __forceinline__ float sigf(float z) { return 1.0f / (1.0f + __expf(-z)); }
__device__ __forceinline__ float tanhf2(float z) { return 2.0f / (1.0f + __expf(-2.0f * z)) - 1.0f; }

__device__ __forceinline__ u32 packh2(float a, float b) {
    union { _Float16 h[2]; u32 u; } q;
    q.h[0] = (_Float16)a; q.h[1] = (_Float16)b;
    return q.u;
}

// ---- coherent comm: sc0 sc1 = bypass L1 AND per-XCD L2; IC is the
// coherence point. Aligned 8B accesses are single-instruction atomic. ----
__device__ __forceinline__ u64 ld64_c(const u64* p) {
    u64 r;
    asm volatile("global_load_dwordx2 %0, %1, off sc0 sc1\n\ts_waitcnt vmcnt(0)"
                 : "=&v"(r) : "v"(p) : "memory");
    return r;
}
__device__ __forceinline__ void st64_c(u64* p, u64 v) {
    asm volatile("global_store_dwordx2 %0, %1, off sc0 sc1" :: "v"(p), "v"(v) : "memory");
}
__device__ __forceinline__ u32 ld32_c(const u32* p) {
    u32 r;
    asm volatile("global_load_dword %0, %1, off sc0 sc1\n\ts_waitcnt vmcnt(0)"
                 : "=&v"(r) : "v"(p) : "memory");
    return r;
}
__device__ __forceinline__ void st32_c(u32* p, u32 v) {
    asm volatile("global_store_dword %0, %1, off sc0 sc1" :: "v"(p), "v"(v) : "memory");
}
__device__ __forceinline__ void ld64x3_c(const u64* p0, const u64* p1, const u64* p2,
                                         u64& r0, u64& r1, u64& r2) {
    asm volatile(
        "global_load_dwordx2 %0, %3, off sc0 sc1\n\t"
        "global_load_dwordx2 %1, %4, off sc0 sc1\n\t"
        "global_load_dwordx2 %2, %5, off sc0 sc1\n\t"
        "s_waitcnt vmcnt(0)"
        : "=&v"(r0), "=&v"(r1), "=&v"(r2)
        : "v"(p0), "v"(p1), "v"(p2)
        : "memory");
}
// merged 7-load batch (L1: 4x h0 + 3x h1 peers), single vmcnt(0)
__device__ __forceinline__ void ld64x7_c(
    const u64* a0, const u64* a1, const u64* a2, const u64* a3,
    const u64* p0, const u64* p1, const u64* p2,
    u64& q0, u64& q1, u64& q2, u64& q3, u64& v0, u64& v1, u64& v2) {
    asm volatile(
        "global_load_dwordx2 %0, %7, off sc0 sc1\n\t"
        "global_load_dwordx2 %1, %8, off sc0 sc1\n\t"
        "global_load_dwordx2 %2, %9, off sc0 sc1\n\t"
        "global_load_dwordx2 %3, %10, off sc0 sc1\n\t"
        "global_load_dwordx2 %4, %11, off sc0 sc1\n\t"
        "global_load_dwordx2 %5, %12, off sc0 sc1\n\t"
        "global_load_dwordx2 %6, %13, off sc0 sc1\n\t"
        "s_waitcnt vmcnt(0)"
        : "=&v"(q0), "=&v"(q1), "=&v"(q2), "=&v"(q3), "=&v"(v0), "=&v"(v1), "=&v"(v2)
        : "v"(a0), "v"(a1), "v"(a2), "v"(a3), "v"(p0), "v"(p1), "v"(p2)
        : "memory");
}

// ---------------------------------------------------------------------------
__global__ void prep_weights(const float* __restrict__ Wih0, const float* __restrict__ Whh0,
                             const float* __restrict__ bih0, const float* __restrict__ bhh0,
                             const float* __restrict__ Wih1, const float* __restrict__ Whh1,
                             const float* __restrict__ bih1, const float* __restrict__ bhh1,
                             _Float16* __restrict__ wcat0, _Float16* __restrict__ wcat1,
                             float* __restrict__ b0, float* __restrict__ b1) {
    int idx0 = blockIdx.x * blockDim.x + threadIdx.x;
    int stride = gridDim.x * blockDim.x;
    for (int i = idx0; i < GATES * K0; i += stride) {
        int n = i / K0, k = i % K0;
        float v = 0.f;
        if (k < HID) v = Whh0[n * HID + k];
        else if (k < HID + IN_DIM) v = Wih0[n * IN_DIM + (k - HID)];
        wcat0[i] = (_Float16)v;
    }
    for (int i = idx0; i < GATES * K1; i += stride) {
        int n = i / K1, k = i % K1;
        float v = (k < HID) ? Whh1[n * HID + k] : Wih1[n * HID + (k - HID)];
        wcat1[i] = (_Float16)v;
    }
    for (int i = idx0; i < GATES; i += stride) {
        b0[i] = bih0[i] + bhh0[i];
        b1[i] = bih1[i] + bhh1[i];
    }
}

// ---------------------------------------------------------------------------
__global__ __launch_bounds__(512) void lstm_scan(
    const float* __restrict__ x, const float* __restrict__ h0g, const float* __restrict__ c0g,
    const _Float16* __restrict__ wcat0, const _Float16* __restrict__ wcat1,
    const float* __restrict__ b0, const float* __restrict__ b1,
    const float* __restrict__ wfc, const float* __restrict__ bfc,
    u64* __restrict__ h0ring, u64* __restrict__ h1ring,
    u32* __restrict__ prog, float* __restrict__ out, int R0) {
    // block decode: group g's 8 WGs at blockIdx in {2g,2g+1}+8k (XCD heuristic)
    const int bi = blockIdx.x;
    const int x7 = bi & 7;
    const int g = x7 >> 1;                       // batch group 0..3
    const int sub = ((x7 & 1) << 2) | (bi >> 3); // 0..7
    const int L = sub >> 2;                      // layer
    const int j = sub & 3;                       // gate slice (64 units)

    const int tid = threadIdx.x;
    const int w = tid >> 6;        // wave 0..7
    const int lane = tid & 63;
    const int quad = lane >> 4;
    const int col = lane & 15;
    const int c0b = g * 16;        // batch base
    const int pm = tid & 15;       // pointwise batch row
    const int iu = tid >> 4;       // pointwise unit-pair index (0..31)
    const int pu = iu * 2;         // pointwise unit base (0..62, local)
    const int gm = tid >> 5;       // gather batch row
    const int gu = tid & 31;       // gather unit-pair

    __shared__ __align__(16) _Float16 Ash[16 * LDA1];
    __shared__ float Gsh[16 * GST];
    __shared__ float WfS[HID];
    __shared__ u32 OwnH[512];

    u64* h0w = h0ring + (size_t)g * R0 * 2048;  // [slot][slice 4][512 tagged words]
    u64* h1w = h1ring + (size_t)g * 4 * 2048;
    const int R0m = R0 - 1;

    int peer[3];
    { int c = 0; for (int p = 0; p < 4; ++p) if (p != j) peer[c++] = p; }

    // Spin-retry budget: steady state burns ~50K retries total; 1<<24 never
    // triggers normally; converts genuine protocol failure into garbage +
    // clean test failure instead of a hang.
    int gbudget = 1 << 24;

    if (L == 0) {
        // ================= layer 0 =================
        half8 wr[2][K0 / 32];
        float bs[2];
#pragma unroll
        for (int tt = 0; tt < 2; ++tt) {
            int t = w + 8 * tt;
            int n = (t >> 2) * 256 + j * 64 + (t & 3) * 16 + col;
            bs[tt] = b0[n];
            const _Float16* wp = wcat0 + (size_t)n * K0 + quad * 8;
#pragma unroll
            for (int kk = 0; kk < K0 / 32; ++kk) wr[tt][kk] = *(const half8*)(wp + kk * 32);
        }
        float cs0 = c0g[(size_t)(c0b + pm) * HID + j * 64 + pu];
        float cs1 = c0g[(size_t)(c0b + pm) * HID + j * 64 + pu + 1];
        {
            int m = tid >> 5, cw = tid & 31;
            const float* hp = h0g + (size_t)(c0b + m) * HID + cw * 8;
            half8 hv;
#pragma unroll
            for (int q2 = 0; q2 < 8; ++q2) hv[q2] = (_Float16)hp[q2];
            *(half8*)&Ash[m * LDA0 + cw * 8] = hv;
            if (cw >= IN_DIM) Ash[m * LDA0 + HID + cw] = (_Float16)0.f;
        }
        const int xm = tid / IN_DIM, xd = tid - xm * IN_DIM;  // for tid<224
        if (tid < 16 * IN_DIM)
            Ash[xm * LDA0 + HID + xd] = (_Float16)x[(size_t)(c0b + xm) * IN_DIM + xd];
        __syncthreads();

        for (int s = 0; s < S_LEN; ++s) {
            // ---- phase A: x prefetch + ring-overrun guard + tag-spin gather
            float xpre = 0.f;
            if (tid < 16 * IN_DIM && s + 1 < S_LEN)
                xpre = x[((size_t)(s + 1) * BATCH + c0b + xm) * IN_DIM + xd];
            if (w == 0 && lane < 4 && (s & 7) == 0 && s + 10 > R0) {
                // L0 may advance up to 8 steps between checks: guard 8+2 ahead
                const u32* np = prog + g * 4 + lane;
                int tgt = s + 10 - R0;
                while ((int)ld32_c(np) < tgt && --gbudget > 0) __builtin_amdgcn_s_sleep(4);
            }
            if (s > 0) {
                const u64* base = h0w + (size_t)((s - 1) & R0m) * 2048;
                const u64* p0 = base + peer[0] * 512 + tid;
                const u64* p1 = base + peer[1] * 512 + tid;
                const u64* p2 = base + peer[2] * 512 + tid;
                u64 v0, v1, v2;
                ld64x3_c(p0, p1, p2, v0, v1, v2);
                const u32 tg = (u32)s;
                while ((u32)(v0 >> 32) != tg && --gbudget > 0) v0 = ld64_c(p0);
                while ((u32)(v1 >> 32) != tg && --gbudget > 0) v1 = ld64_c(p1);
                while ((u32)(v2 >> 32) != tg && --gbudget > 0) v2 = ld64_c(p2);
                *(u32*)&Ash[gm * LDA0 + peer[0] * 64 + 2 * gu] = (u32)v0;
                *(u32*)&Ash[gm * LDA0 + peer[1] * 64 + 2 * gu] = (u32)v1;
                *(u32*)&Ash[gm * LDA0 + peer[2] * 64 + 2 * gu] = (u32)v2;
            }
            __syncthreads();
            // ---- phase B: MFMA -> gates
            f32x4 acc0 = {bs[0], bs[0], bs[0], bs[0]};
            f32x4 acc1 = {bs[1], bs[1], bs[1], bs[1]};
#pragma unroll
            for (int kk = 0; kk < K0 / 32; ++kk) {
                half8 av = *(const half8*)&Ash[col * LDA0 + kk * 32 + quad * 8];
                acc0 = __builtin_amdgcn_mfma_f32_16x16x32_f16(av, wr[0][kk], acc0, 0, 0, 0);
                acc1 = __builtin_amdgcn_mfma_f32_16x16x32_f16(av, wr[1][kk], acc1, 0, 0, 0);
            }
#pragma unroll
            for (int r = 0; r < 4; ++r) {
                Gsh[(quad * 4 + r) * GST + w * 16 + col] = acc0[r];
                Gsh[(quad * 4 + r) * GST + (w + 8) * 16 + col] = acc1[r];
            }
            __syncthreads();
            // ---- phase C: pointwise + publish (fire-and-forget tagged store)
            {
                float iv = sigf(Gsh[pm * GST + pu]);
                float fv = sigf(Gsh[pm * GST + 64 + pu]);
                float gv = tanhf2(Gsh[pm * GST + 128 + pu]);
                float ov = sigf(Gsh[pm * GST + 192 + pu]);
                cs0 = fv * cs0 + iv * gv;
                float ha = ov * tanhf2(cs0);
                iv = sigf(Gsh[pm * GST + pu + 1]);
                fv = sigf(Gsh[pm * GST + 64 + pu + 1]);
                gv = tanhf2(Gsh[pm * GST + 128 + pu + 1]);
                ov = sigf(Gsh[pm * GST + 192 + pu + 1]);
                cs1 = fv * cs1 + iv * gv;
                float hb = ov * tanhf2(cs1);
                u32 hw = packh2(ha, hb);
                *(u32*)&Ash[pm * LDA0 + j * 64 + pu] = hw;
                st64_c(h0w + (size_t)(s & R0m) * 2048 + j * 512 + (pm * 32 + iu),
                       (u64)hw | ((u64)(u32)(s + 1) << 32));
            }
            if (tid < 16 * IN_DIM && s + 1 < S_LEN)
                Ash[xm * LDA0 + HID + xd] = (_Float16)xpre;
            __syncthreads();
        }
    } else {
        // ================= layer 1 + fused FC =================
        half8 wr[2][K1 / 32];
        float bs[2];
#pragma unroll
        for (int tt = 0; tt < 2; ++tt) {
            int t = w + 8 * tt;
            int n = (t >> 2) * 256 + j * 64 + (t & 3) * 16 + col;
            bs[tt] = b1[n];
            const _Float16* wp = wcat1 + (size_t)n * K1 + quad * 8;
#pragma unroll
            for (int kk = 0; kk < K1 / 32; ++kk) wr[tt][kk] = *(const half8*)(wp + kk * 32);
        }
        for (int i = tid; i < HID; i += 512) WfS[i] = wfc[i];
        const float bfcv = bfc[0];
        float cs0 = c0g[(size_t)(BATCH + c0b + pm) * HID + j * 64 + pu];
        float cs1 = c0g[(size_t)(BATCH + c0b + pm) * HID + j * 64 + pu + 1];
        {
            int m = tid >> 5, cw = tid & 31;
            const float* hp = h0g + (size_t)(BATCH + c0b + m) * HID + cw * 8;
            half8 hv;
#pragma unroll
            for (int q2 = 0; q2 < 8; ++q2) hv[q2] = (_Float16)hp[q2];
            *(half8*)&Ash[m * LDA1 + cw * 8] = hv;
        }
        u32* progself = prog + g * 4 + j;
        __syncthreads();

        for (int s = 0; s <= S_LEN; ++s) {
            // ---- phase A: FC on Ash snapshot (h1[s-2]) + batched gather + spin
            if (w == 7 && s >= 2) {
                int m = 4 * j + quad;
                float fa = 0.f;
#pragma unroll
                for (int k16 = 0; k16 < 16; ++k16) {
                    float hv = (float)Ash[m * LDA1 + col + 16 * k16];
                    fa += fmaxf(hv, 0.f) * WfS[col + 16 * k16];
                }
#pragma unroll
                for (int off = 1; off < 16; off <<= 1) fa += __shfl_xor(fa, off, 16);
                if (col == 0) out[(size_t)(s - 2) * BATCH + c0b + m] = fa + bfcv;
            }
            // h0[s] words (dummy base when s==S_LEN; values unused then)
            const u64* hb = h0w + (size_t)((s < S_LEN ? s : 0) & R0m) * 2048;
            const u64* a0 = hb + tid;
            const u64* a1 = hb + 512 + tid;
            const u64* a2 = hb + 1024 + tid;
            const u64* a3 = hb + 1536 + tid;
            // h1[s-1] peer words (dummy base when s==0; values unused then)
            const u64* pb = h1w + (size_t)(((s > 0 ? s : 1) - 1) & 3) * 2048;
            const u64* p0 = pb + peer[0] * 512 + tid;
            const u64* p1 = pb + peer[1] * 512 + tid;
            const u64* p2 = pb + peer[2] * 512 + tid;
            u64 q0, q1, q2, q3, v0, v1, v2;
            ld64x7_c(a0, a1, a2, a3, p0, p1, p2, q0, q1, q2, q3, v0, v1, v2);
            if (s < S_LEN) {   // validate h0[s] (L0 runs ahead; usually instant)
                const u32 tg = (u32)(s + 1);
                while ((u32)(q0 >> 32) != tg && --gbudget > 0) q0 = ld64_c(a0);
                while ((u32)(q1 >> 32) != tg && --gbudget > 0) q1 = ld64_c(a1);
                while ((u32)(q2 >> 32) != tg && --gbudget > 0) q2 = ld64_c(a2);
                while ((u32)(q3 >> 32) != tg && --gbudget > 0) q3 = ld64_c(a3);
            }
            if (s > 0) {       // validate h1[s-1] peers
                const u32 tg = (u32)s;
                while ((u32)(v0 >> 32) != tg && --gbudget > 0) v0 = ld64_c(p0);
                while ((u32)(v1 >> 32) != tg && --gbudget > 0) v1 = ld64_c(p1);
                while ((u32)(v2 >> 32) != tg && --gbudget > 0) v2 = ld64_c(p2);
            }
            __syncthreads();
            // ---- phase B: commit gathers to Ash (own slice via OwnH -> FC snapshot)
            if (s > 0) {
                *(u32*)&Ash[gm * LDA1 + peer[0] * 64 + 2 * gu] = (u32)v0;
                *(u32*)&Ash[gm * LDA1 + peer[1] * 64 + 2 * gu] = (u32)v1;
                *(u32*)&Ash[gm * LDA1 + peer[2] * 64 + 2 * gu] = (u32)v2;
                *(u32*)&Ash[gm * LDA1 + j * 64 + 2 * gu] = OwnH[tid];
            }
            if (s < S_LEN) {
                *(u32*)&Ash[gm * LDA1 + HID + 0 * 64 + 2 * gu] = (u32)q0;
                *(u32*)&Ash[gm * LDA1 + HID + 1 * 64 + 2 * gu] = (u32)q1;
                *(u32*)&Ash[gm * LDA1 + HID + 2 * 64 + 2 * gu] = (u32)q2;
                *(u32*)&Ash[gm * LDA1 + HID + 3 * 64 + 2 * gu] = (u32)q3;
            }
            __syncthreads();
            if (s == S_LEN) {
                if (w == 7) {  // final FC on h1[S_LEN-1]
                    int m = 4 * j + quad;
                    float fa = 0.f;
#pragma unroll
                    for (int k16 = 0; k16 < 16; ++k16) {
                        float hv = (float)Ash[m * LDA1 + col + 16 * k16];
                        fa += fmaxf(hv, 0.f) * WfS[col + 16 * k16];
                    }
#pragma unroll
                    for (int off = 1; off < 16; off <<= 1) fa += __shfl_xor(fa, off, 16);
                    if (col == 0) out[(size_t)(S_LEN - 1) * BATCH + c0b + m] = fa + bfcv;
                }
                break;
            }
            // ---- phase C: MFMA -> gates
            f32x4 acc0 = {bs[0], bs[0], bs[0], bs[0]};
            f32x4 acc1 = {bs[1], bs[1], bs[1], bs[1]};
#pragma unroll
            for (int kk = 0; kk < K1 / 32; ++kk) {
                half8 av = *(const half8*)&Ash[col * LDA1 + kk * 32 + quad * 8];
                acc0 = __builtin_amdgcn_mfma_f32_16x16x32_f16(av, wr[0][kk], acc0, 0, 0, 0);
                acc1 = __builtin_amdgcn_mfma_f32_16x16x32_f16(av, wr[1][kk], acc1, 0, 0, 0);
            }
#pragma unroll
            for (int r = 0; r < 4; ++r) {
                Gsh[(quad * 4 + r) * GST + w * 16 + col] = acc0[r];
                Gsh[(quad * 4 + r) * GST + (w + 8) * 16 + col] = acc1[r];
            }
            __syncthreads();
            // ---- phase D: pointwise + publish + progress post
            {
                float iv = sigf(Gsh[pm * GST + pu]);
                float fv = sigf(Gsh[pm * GST + 64 + pu]);
                float gv = tanhf2(Gsh[pm * GST + 128 + pu]);
                float ov = sigf(Gsh[pm * GST + 192 + pu]);
                cs0 = fv * cs0 + iv * gv;
                float ha = ov * tanhf2(cs0);
                iv = sigf(Gsh[pm * GST + pu + 1]);
                fv = sigf(Gsh[pm * GST + 64 + pu + 1]);
                gv = tanhf2(Gsh[pm * GST + 128 + pu + 1]);
                ov = sigf(Gsh[pm * GST + 192 + pu + 1]);
                cs1 = fv * cs1 + iv * gv;
                float hb = ov * tanhf2(cs1);
                u32 hw = packh2(ha, hb);
                OwnH[pm * 32 + iu] = hw;   // defer own-slice Ash update (FC snapshot)
                st64_c(h1w + (size_t)(s & 3) * 2048 + j * 512 + (pm * 32 + iu),
                       (u64)hw | ((u64)(u32)(s + 1) << 32));
            }
            if ((s & 7) == 7 && tid == 0) st32_c(progself, (u32)(s + 1));
            __syncthreads();
        }
    }
}

// ---------------------------------------------------------------------------
extern "C" void kernel_launch(void* const* d_in, const int* in_sizes, int n_in,
                              void* d_out, int out_size, void* d_ws, size_t ws_size,
                              hipStream_t stream) {
    const float* x    = (const float*)d_in[0];
    const float* h0   = (const float*)d_in[1];
    const float* c0   = (const float*)d_in[2];
    const float* Wih0 = (const float*)d_in[3];
    const float* Whh0 = (const float*)d_in[4];
    const float* bih0 = (const float*)d_in[5];
    const float* bhh0 = (const float*)d_in[6];
    const float* Wih1 = (const float*)d_in[7];
    const float* Whh1 = (const float*)d_in[8];
    const float* bih1 = (const float*)d_in[9];
    const float* bhh1 = (const float*)d_in[10];
    const float* Wfc  = (const float*)d_in[11];
    const float* bfc  = (const float*)d_in[12];
    float* out = (float*)d_out;

    char* ws = (char*)d_ws;
    constexpr size_t OFF_WCAT0 = 0;
    constexpr size_t SZ_WCAT0 = (size_t)GATES * K0 * 2;   // 576 KB
    constexpr size_t OFF_WCAT1 = OFF_WCAT0 + SZ_WCAT0;
    constexpr size_t SZ_WCAT1 = (size_t)GATES * K1 * 2;   // 1 MB
    constexpr size_t OFF_B0 = OFF_WCAT1 + SZ_WCAT1;
    constexpr size_t OFF_B1 = OFF_B0 + 4096;
    constexpr size_t OFF_PROG = OFF_B1 + 4096;            // zeroed region starts here
    constexpr size_t OFF_H1R = OFF_PROG + 4096;
    constexpr size_t SZ_H1R = (size_t)4 * 4 * 2048 * 8;   // 256 KB
    constexpr size_t OFF_H0R = OFF_H1R + SZ_H1R;

    _Float16* wcat0 = (_Float16*)(ws + OFF_WCAT0);
    _Float16* wcat1 = (_Float16*)(ws + OFF_WCAT1);
    float* b0 = (float*)(ws + OFF_B0);
    float* b1 = (float*)(ws + OFF_B1);
    u32* prog = (u32*)(ws + OFF_PROG);
    u64* h1ring = (u64*)(ws + OFF_H1R);

    int R0 = 128;  // h0 ring slots; per group slot = 16 KB (tagged words)
    while (OFF_H0R + (size_t)4 * R0 * 2048 * 8 > ws_size && R0 > 16) R0 >>= 1;
    u64* h0ring = (u64*)(ws + OFF_H0R);

    // zero prog + both rings every launch (kills stale-tag acceptance across
    // graph replays)
    hipMemsetAsync(ws + OFF_PROG, 0,
                   (OFF_H0R - OFF_PROG) + (size_t)4 * R0 * 2048 * 8, stream);
    prep_weights<<<256, 256, 0, stream>>>(Wih0, Whh0, bih0, bhh0, Wih1, Whh1, bih1, bhh1,
                                          wcat0, wcat1, b0, b1);
    lstm_scan<<<32, 512, 0, stream>>>(x, h0, c0, wcat0, wcat1, b0, b1, Wfc, bfc,
                                      h0ring, h1ring, prog, out, R0);
}

// Round 5
// 10257.185 us; speedup vs baseline: 1.1228x; 1.0467x over previous
//
#include <hip/hip_runtime.h>

// ---------------------------------------------------------------------------
// 2-layer LSTM (S=4096, B=64, I=14, H=256) + ReLU + FC(256->1), eval mode.
// R9 = R8 (tag-in-data protocol, sc0 sc1 coherent transport) + latency cuts:
//  - GST 260->261: pointwise Gsh reads were 4-way bank-conflicted (even banks
//    only; SQ_LDS_BANK_CONFLICT ~610 cy/WG-step). Stride 261 -> bank stride 5
//    (coprime 32) -> <=2-way (free).
//  - Round-batched tag revalidation: reload ALL gather words in one vmcnt(0)
//    batch per round instead of serial per-word retry chains (was up to
//    3x/7x ~700cy serialized). Idempotent: slot epochs can't advance while
//    the consumer spins (h1 needs my future publishes; h0 is prog-guarded).
//  - L0 end-of-step barrier removed (phase-C Ash writes are disjoint from
//    next phase-A writes; all meet at the gather barrier before MFMA).
// (Round 4 resubmit: prior bench was an infra failure — container acquisition
//  failed twice; no test output. Kernel cannot hang: all spins share a
//  bounded retry budget.)
// ---------------------------------------------------------------------------

#define S_LEN 4096
#define BATCH 64
#define IN_DIM 14
#define HID 256
#define GATES 1024
#define K0 288        // layer0 K (h256 | x14 | pad18)
#define LDA0 296      // LDS A row stride (f16), layer0
#define K1 512        // layer1 K (h1 | hs0)
#define LDA1 520      // LDS A row stride (f16), layer1
#define GST 261       // gate LDS row stride (f32): bank stride 5 -> <=2-way

typedef _Float16 half8 __attribute__((ext_vector_type(8)));
typedef float f32x4 __attribute__((ext_vector_type(4)));
typedef unsigned long long u64;
typedef unsigned int u32;

__device__ __forceinline__ float sigf(float z) { return 1.0f / (1.0f + __expf(-z)); }
__device__ __forceinline__ float tanhf2(float z) { return 2.0f / (1.0f + __expf(-2.0f * z)) - 1.0f; }

__device__ __forceinline__ u32 packh2(float a, float b) {
    union { _Float16 h[2]; u32 u; } q;
    q.h[0] = (_Float16)a; q.h[1] = (_Float16)b;
    return q.u;
}

// ---- coherent comm: sc0 sc1 = bypass L1 AND per-XCD L2; IC is the
// coherence point. Aligned 8B accesses are single-instruction atomic. ----
__device__ __forceinline__ u32 ld32_c(const u32* p) {
    u32 r;
    asm volatile("global_load_dword %0, %1, off sc0 sc1\n\ts_waitcnt vmcnt(0)"
                 : "=&v"(r) : "v"(p) : "memory");
    return r;
}
__device__ __forceinline__ void st32_c(u32* p, u32 v) {
    asm volatile("global_store_dword %0, %1, off sc0 sc1" :: "v"(p), "v"(v) : "memory");
}
__device__ __forceinline__ void st64_c(u64* p, u64 v) {
    asm volatile("global_store_dwordx2 %0, %1, off sc0 sc1" :: "v"(p), "v"(v) : "memory");
}
__device__ __forceinline__ void ld64x3_c(const u64* p0, const u64* p1, const u64* p2,
                                         u64& r0, u64& r1, u64& r2) {
    asm volatile(
        "global_load_dwordx2 %0, %3, off sc0 sc1\n\t"
        "global_load_dwordx2 %1, %4, off sc0 sc1\n\t"
        "global_load_dwordx2 %2, %5, off sc0 sc1\n\t"
        "s_waitcnt vmcnt(0)"
        : "=&v"(r0), "=&v"(r1), "=&v"(r2)
        : "v"(p0), "v"(p1), "v"(p2)
        : "memory");
}
// merged 7-load batch (L1: 4x h0 + 3x h1 peers), single vmcnt(0)
__device__ __forceinline__ void ld64x7_c(
    const u64* a0, const u64* a1, const u64* a2, const u64* a3,
    const u64* p0, const u64* p1, const u64* p2,
    u64& q0, u64& q1, u64& q2, u64& q3, u64& v0, u64& v1, u64& v2) {
    asm volatile(
        "global_load_dwordx2 %0, %7, off sc0 sc1\n\t"
        "global_load_dwordx2 %1, %8, off sc0 sc1\n\t"
        "global_load_dwordx2 %2, %9, off sc0 sc1\n\t"
        "global_load_dwordx2 %3, %10, off sc0 sc1\n\t"
        "global_load_dwordx2 %4, %11, off sc0 sc1\n\t"
        "global_load_dwordx2 %5, %12, off sc0 sc1\n\t"
        "global_load_dwordx2 %6, %13, off sc0 sc1\n\t"
        "s_waitcnt vmcnt(0)"
        : "=&v"(q0), "=&v"(q1), "=&v"(q2), "=&v"(q3), "=&v"(v0), "=&v"(v1), "=&v"(v2)
        : "v"(a0), "v"(a1), "v"(a2), "v"(a3), "v"(p0), "v"(p1), "v"(p2)
        : "memory");
}

// ---------------------------------------------------------------------------
__global__ void prep_weights(const float* __restrict__ Wih0, const float* __restrict__ Whh0,
                             const float* __restrict__ bih0, const float* __restrict__ bhh0,
                             const float* __restrict__ Wih1, const float* __restrict__ Whh1,
                             const float* __restrict__ bih1, const float* __restrict__ bhh1,
                             _Float16* __restrict__ wcat0, _Float16* __restrict__ wcat1,
                             float* __restrict__ b0, float* __restrict__ b1) {
    int idx0 = blockIdx.x * blockDim.x + threadIdx.x;
    int stride = gridDim.x * blockDim.x;
    for (int i = idx0; i < GATES * K0; i += stride) {
        int n = i / K0, k = i % K0;
        float v = 0.f;
        if (k < HID) v = Whh0[n * HID + k];
        else if (k < HID + IN_DIM) v = Wih0[n * IN_DIM + (k - HID)];
        wcat0[i] = (_Float16)v;
    }
    for (int i = idx0; i < GATES * K1; i += stride) {
        int n = i / K1, k = i % K1;
        float v = (k < HID) ? Whh1[n * HID + k] : Wih1[n * HID + (k - HID)];
        wcat1[i] = (_Float16)v;
    }
    for (int i = idx0; i < GATES; i += stride) {
        b0[i] = bih0[i] + bhh0[i];
        b1[i] = bih1[i] + bhh1[i];
    }
}

// ---------------------------------------------------------------------------
__global__ __launch_bounds__(512) void lstm_scan(
    const float* __restrict__ x, const float* __restrict__ h0g, const float* __restrict__ c0g,
    const _Float16* __restrict__ wcat0, const _Float16* __restrict__ wcat1,
    const float* __restrict__ b0, const float* __restrict__ b1,
    const float* __restrict__ wfc, const float* __restrict__ bfc,
    u64* __restrict__ h0ring, u64* __restrict__ h1ring,
    u32* __restrict__ prog, float* __restrict__ out, int R0) {
    // block decode: group g's 8 WGs at blockIdx in {2g,2g+1}+8k (XCD heuristic)
    const int bi = blockIdx.x;
    const int x7 = bi & 7;
    const int g = x7 >> 1;                       // batch group 0..3
    const int sub = ((x7 & 1) << 2) | (bi >> 3); // 0..7
    const int L = sub >> 2;                      // layer
    const int j = sub & 3;                       // gate slice (64 units)

    const int tid = threadIdx.x;
    const int w = tid >> 6;        // wave 0..7
    const int lane = tid & 63;
    const int quad = lane >> 4;
    const int col = lane & 15;
    const int c0b = g * 16;        // batch base
    const int pm = tid & 15;       // pointwise batch row
    const int iu = tid >> 4;       // pointwise unit-pair index (0..31)
    const int pu = iu * 2;         // pointwise unit base (0..62, local)
    const int gm = tid >> 5;       // gather batch row
    const int gu = tid & 31;       // gather unit-pair

    __shared__ __align__(16) _Float16 Ash[16 * LDA1];
    __shared__ float Gsh[16 * GST];
    __shared__ float WfS[HID];
    __shared__ u32 OwnH[512];

    u64* h0w = h0ring + (size_t)g * R0 * 2048;  // [slot][slice 4][512 tagged words]
    u64* h1w = h1ring + (size_t)g * 4 * 2048;
    const int R0m = R0 - 1;

    int peer[3];
    { int c = 0; for (int p = 0; p < 4; ++p) if (p != j) peer[c++] = p; }

    // Spin budget counts RETRY ROUNDS (each ~700cy). Steady state uses
    // 1-3 rounds/step (~12K total). 1<<22 never triggers normally; converts
    // genuine protocol failure into garbage + clean test failure, not a hang.
    int gbudget = 1 << 22;

    if (L == 0) {
        // ================= layer 0 =================
        half8 wr[2][K0 / 32];
        float bs[2];
#pragma unroll
        for (int tt = 0; tt < 2; ++tt) {
            int t = w + 8 * tt;
            int n = (t >> 2) * 256 + j * 64 + (t & 3) * 16 + col;
            bs[tt] = b0[n];
            const _Float16* wp = wcat0 + (size_t)n * K0 + quad * 8;
#pragma unroll
            for (int kk = 0; kk < K0 / 32; ++kk) wr[tt][kk] = *(const half8*)(wp + kk * 32);
        }
        float cs0 = c0g[(size_t)(c0b + pm) * HID + j * 64 + pu];
        float cs1 = c0g[(size_t)(c0b + pm) * HID + j * 64 + pu + 1];
        {
            int m = tid >> 5, cw = tid & 31;
            const float* hp = h0g + (size_t)(c0b + m) * HID + cw * 8;
            half8 hv;
#pragma unroll
            for (int q2 = 0; q2 < 8; ++q2) hv[q2] = (_Float16)hp[q2];
            *(half8*)&Ash[m * LDA0 + cw * 8] = hv;
            if (cw >= IN_DIM) Ash[m * LDA0 + HID + cw] = (_Float16)0.f;
        }
        const int xm = tid / IN_DIM, xd = tid - xm * IN_DIM;  // for tid<224
        if (tid < 16 * IN_DIM)
            Ash[xm * LDA0 + HID + xd] = (_Float16)x[(size_t)(c0b + xm) * IN_DIM + xd];
        __syncthreads();

        for (int s = 0; s < S_LEN; ++s) {
            // ---- phase A: x prefetch + ring-overrun guard + batched tag spin
            float xpre = 0.f;
            if (tid < 16 * IN_DIM && s + 1 < S_LEN)
                xpre = x[((size_t)(s + 1) * BATCH + c0b + xm) * IN_DIM + xd];
            if (w == 0 && lane < 4 && (s & 7) == 0 && s + 10 > R0) {
                // L0 may advance up to 8 steps between checks: guard 8+2 ahead
                const u32* np = prog + g * 4 + lane;
                int tgt = s + 10 - R0;
                while ((int)ld32_c(np) < tgt && --gbudget > 0) __builtin_amdgcn_s_sleep(4);
            }
            if (s > 0) {
                const u64* base = h0w + (size_t)((s - 1) & R0m) * 2048;
                const u64* p0 = base + peer[0] * 512 + tid;
                const u64* p1 = base + peer[1] * 512 + tid;
                const u64* p2 = base + peer[2] * 512 + tid;
                u64 v0, v1, v2;
                ld64x3_c(p0, p1, p2, v0, v1, v2);
                const u32 tg = (u32)s;
                while ((((u32)(v0 >> 32) != tg) | ((u32)(v1 >> 32) != tg) |
                        ((u32)(v2 >> 32) != tg)) && --gbudget > 0)
                    ld64x3_c(p0, p1, p2, v0, v1, v2);   // reload ALL per round
                *(u32*)&Ash[gm * LDA0 + peer[0] * 64 + 2 * gu] = (u32)v0;
                *(u32*)&Ash[gm * LDA0 + peer[1] * 64 + 2 * gu] = (u32)v1;
                *(u32*)&Ash[gm * LDA0 + peer[2] * 64 + 2 * gu] = (u32)v2;
            }
            __syncthreads();
            // ---- phase B: MFMA -> gates
            f32x4 acc0 = {bs[0], bs[0], bs[0], bs[0]};
            f32x4 acc1 = {bs[1], bs[1], bs[1], bs[1]};
#pragma unroll
            for (int kk = 0; kk < K0 / 32; ++kk) {
                half8 av = *(const half8*)&Ash[col * LDA0 + kk * 32 + quad * 8];
                acc0 = __builtin_amdgcn_mfma_f32_16x16x32_f16(av, wr[0][kk], acc0, 0, 0, 0);
                acc1 = __builtin_amdgcn_mfma_f32_16x16x32_f16(av, wr[1][kk], acc1, 0, 0, 0);
            }
#pragma unroll
            for (int r = 0; r < 4; ++r) {
                Gsh[(quad * 4 + r) * GST + w * 16 + col] = acc0[r];
                Gsh[(quad * 4 + r) * GST + (w + 8) * 16 + col] = acc1[r];
            }
            __syncthreads();
            // ---- phase C: pointwise + publish (fire-and-forget tagged store)
            {
                float iv = sigf(Gsh[pm * GST + pu]);
                float fv = sigf(Gsh[pm * GST + 64 + pu]);
                float gv = tanhf2(Gsh[pm * GST + 128 + pu]);
                float ov = sigf(Gsh[pm * GST + 192 + pu]);
                cs0 = fv * cs0 + iv * gv;
                float ha = ov * tanhf2(cs0);
                iv = sigf(Gsh[pm * GST + pu + 1]);
                fv = sigf(Gsh[pm * GST + 64 + pu + 1]);
                gv = tanhf2(Gsh[pm * GST + 128 + pu + 1]);
                ov = sigf(Gsh[pm * GST + 192 + pu + 1]);
                cs1 = fv * cs1 + iv * gv;
                float hb = ov * tanhf2(cs1);
                u32 hw = packh2(ha, hb);
                *(u32*)&Ash[pm * LDA0 + j * 64 + pu] = hw;
                st64_c(h0w + (size_t)(s & R0m) * 2048 + j * 512 + (pm * 32 + iu),
                       (u64)hw | ((u64)(u32)(s + 1) << 32));
            }
            if (tid < 16 * IN_DIM && s + 1 < S_LEN)
                Ash[xm * LDA0 + HID + xd] = (_Float16)xpre;
            // no end-of-step barrier: phase-C Ash writes (own slice + x) are
            // disjoint from next phase-A writes (peer slices); the gather
            // barrier orders everything before the next MFMA.
        }
    } else {
        // ================= layer 1 + fused FC =================
        half8 wr[2][K1 / 32];
        float bs[2];
#pragma unroll
        for (int tt = 0; tt < 2; ++tt) {
            int t = w + 8 * tt;
            int n = (t >> 2) * 256 + j * 64 + (t & 3) * 16 + col;
            bs[tt] = b1[n];
            const _Float16* wp = wcat1 + (size_t)n * K1 + quad * 8;
#pragma unroll
            for (int kk = 0; kk < K1 / 32; ++kk) wr[tt][kk] = *(const half8*)(wp + kk * 32);
        }
        for (int i = tid; i < HID; i += 512) WfS[i] = wfc[i];
        const float bfcv = bfc[0];
        float cs0 = c0g[(size_t)(BATCH + c0b + pm) * HID + j * 64 + pu];
        float cs1 = c0g[(size_t)(BATCH + c0b + pm) * HID + j * 64 + pu + 1];
        {
            int m = tid >> 5, cw = tid & 31;
            const float* hp = h0g + (size_t)(BATCH + c0b + m) * HID + cw * 8;
            half8 hv;
#pragma unroll
            for (int q2 = 0; q2 < 8; ++q2) hv[q2] = (_Float16)hp[q2];
            *(half8*)&Ash[m * LDA1 + cw * 8] = hv;
        }
        u32* progself = prog + g * 4 + j;
        __syncthreads();

        for (int s = 0; s <= S_LEN; ++s) {
            // ---- phase A: FC on Ash snapshot (h1[s-2]) + batched gather + spin
            if (w == 7 && s >= 2) {
                int m = 4 * j + quad;
                float fa = 0.f;
#pragma unroll
                for (int k16 = 0; k16 < 16; ++k16) {
                    float hv = (float)Ash[m * LDA1 + col + 16 * k16];
                    fa += fmaxf(hv, 0.f) * WfS[col + 16 * k16];
                }
#pragma unroll
                for (int off = 1; off < 16; off <<= 1) fa += __shfl_xor(fa, off, 16);
                if (col == 0) out[(size_t)(s - 2) * BATCH + c0b + m] = fa + bfcv;
            }
            // h0[s] words (dummy base when s==S_LEN; values unused then)
            const u64* hb = h0w + (size_t)((s < S_LEN ? s : 0) & R0m) * 2048;
            const u64* a0 = hb + tid;
            const u64* a1 = hb + 512 + tid;
            const u64* a2 = hb + 1024 + tid;
            const u64* a3 = hb + 1536 + tid;
            // h1[s-1] peer words (dummy base when s==0; values unused then)
            const u64* pb = h1w + (size_t)(((s > 0 ? s : 1) - 1) & 3) * 2048;
            const u64* p0 = pb + peer[0] * 512 + tid;
            const u64* p1 = pb + peer[1] * 512 + tid;
            const u64* p2 = pb + peer[2] * 512 + tid;
            u64 q0, q1, q2, q3, v0, v1, v2;
            ld64x7_c(a0, a1, a2, a3, p0, p1, p2, q0, q1, q2, q3, v0, v1, v2);
            {
                const u32 tgq = (u32)(s + 1), tgv = (u32)s;
                for (;;) {
                    bool bad = false;
                    if (s < S_LEN)
                        bad |= ((u32)(q0 >> 32) != tgq) | ((u32)(q1 >> 32) != tgq) |
                               ((u32)(q2 >> 32) != tgq) | ((u32)(q3 >> 32) != tgq);
                    if (s > 0)
                        bad |= ((u32)(v0 >> 32) != tgv) | ((u32)(v1 >> 32) != tgv) |
                               ((u32)(v2 >> 32) != tgv);
                    if (!bad || --gbudget <= 0) break;
                    ld64x7_c(a0, a1, a2, a3, p0, p1, p2, q0, q1, q2, q3, v0, v1, v2);
                }
            }
            __syncthreads();
            // ---- phase B: commit gathers to Ash (own slice via OwnH -> FC snapshot)
            if (s > 0) {
                *(u32*)&Ash[gm * LDA1 + peer[0] * 64 + 2 * gu] = (u32)v0;
                *(u32*)&Ash[gm * LDA1 + peer[1] * 64 + 2 * gu] = (u32)v1;
                *(u32*)&Ash[gm * LDA1 + peer[2] * 64 + 2 * gu] = (u32)v2;
                *(u32*)&Ash[gm * LDA1 + j * 64 + 2 * gu] = OwnH[tid];
            }
            if (s < S_LEN) {
                *(u32*)&Ash[gm * LDA1 + HID + 0 * 64 + 2 * gu] = (u32)q0;
                *(u32*)&Ash[gm * LDA1 + HID + 1 * 64 + 2 * gu] = (u32)q1;
                *(u32*)&Ash[gm * LDA1 + HID + 2 * 64 + 2 * gu] = (u32)q2;
                *(u32*)&Ash[gm * LDA1 + HID + 3 * 64 + 2 * gu] = (u32)q3;
            }
            __syncthreads();
            if (s == S_LEN) {
                if (w == 7) {  // final FC on h1[S_LEN-1]
                    int m = 4 * j + quad;
                    float fa = 0.f;
#pragma unroll
                    for (int k16 = 0; k16 < 16; ++k16) {
                        float hv = (float)Ash[m * LDA1 + col + 16 * k16];
                        fa += fmaxf(hv, 0.f) * WfS[col + 16 * k16];
                    }
#pragma unroll
                    for (int off = 1; off < 16; off <<= 1) fa += __shfl_xor(fa, off, 16);
                    if (col == 0) out[(size_t)(S_LEN - 1) * BATCH + c0b + m] = fa + bfcv;
                }
                break;
            }
            // ---- phase C: MFMA -> gates
            f32x4 acc0 = {bs[0], bs[0], bs[0], bs[0]};
            f32x4 acc1 = {bs[1], bs[1], bs[1], bs[1]};
#pragma unroll
            for (int kk = 0; kk < K1 / 32; ++kk) {
                half8 av = *(const half8*)&Ash[col * LDA1 + kk * 32 + quad * 8];
                acc0 = __builtin_amdgcn_mfma_f32_16x16x32_f16(av, wr[0][kk], acc0, 0, 0, 0);
                acc1 = __builtin_amdgcn_mfma_f32_16x16x32_f16(av, wr[1][kk], acc1, 0, 0, 0);
            }
#pragma unroll
            for (int r = 0; r < 4; ++r) {
                Gsh[(quad * 4 + r) * GST + w * 16 + col] = acc0[r];
                Gsh[(quad * 4 + r) * GST + (w + 8) * 16 + col] = acc1[r];
            }
            __syncthreads();
            // ---- phase D: pointwise + publish + progress post
            {
                float iv = sigf(Gsh[pm * GST + pu]);
                float fv = sigf(Gsh[pm * GST + 64 + pu]);
                float gv = tanhf2(Gsh[pm * GST + 128 + pu]);
                float ov = sigf(Gsh[pm * GST + 192 + pu]);
                cs0 = fv * cs0 + iv * gv;
                float ha = ov * tanhf2(cs0);
                iv = sigf(Gsh[pm * GST + pu + 1]);
                fv = sigf(Gsh[pm * GST + 64 + pu + 1]);
                gv = tanhf2(Gsh[pm * GST + 128 + pu + 1]);
                ov = sigf(Gsh[pm * GST + 192 + pu + 1]);
                cs1 = fv * cs1 + iv * gv;
                float hb = ov * tanhf2(cs1);
                u32 hw = packh2(ha, hb);
                OwnH[pm * 32 + iu] = hw;   // defer own-slice Ash update (FC snapshot)
                st64_c(h1w + (size_t)(s & 3) * 2048 + j * 512 + (pm * 32 + iu),
                       (u64)hw | ((u64)(u32)(s + 1) << 32));
            }
            if ((s & 7) == 7 && tid == 0) st32_c(progself, (u32)(s + 1));
            __syncthreads();   // needed: OwnH is a cross-thread transpose
        }
    }
}

// ---------------------------------------------------------------------------
extern "C" void kernel_launch(void* const* d_in, const int* in_sizes, int n_in,
                              void* d_out, int out_size, void* d_ws, size_t ws_size,
                              hipStream_t stream) {
    const float* x    = (const float*)d_in[0];
    const float* h0   = (const float*)d_in[1];
    const float* c0   = (const float*)d_in[2];
    const float* Wih0 = (const float*)d_in[3];
    const float* Whh0 = (const float*)d_in[4];
    const float* bih0 = (const float*)d_in[5];
    const float* bhh0 = (const float*)d_in[6];
    const float* Wih1 = (const float*)d_in[7];
    const float* Whh1 = (const float*)d_in[8];
    const float* bih1 = (const float*)d_in[9];
    const float* bhh1 = (const float*)d_in[10];
    const float* Wfc  = (const float*)d_in[11];
    const float* bfc  = (const float*)d_in[12];
    float* out = (float*)d_out;

    char* ws = (char*)d_ws;
    constexpr size_t OFF_WCAT0 = 0;
    constexpr size_t SZ_WCAT0 = (size_t)GATES * K0 * 2;   // 576 KB
    constexpr size_t OFF_WCAT1 = OFF_WCAT0 + SZ_WCAT0;
    constexpr size_t SZ_WCAT1 = (size_t)GATES * K1 * 2;   // 1 MB
    constexpr size_t OFF_B0 = OFF_WCAT1 + SZ_WCAT1;
    constexpr size_t OFF_B1 = OFF_B0 + 4096;
    constexpr size_t OFF_PROG = OFF_B1 + 4096;            // zeroed region starts here
    constexpr size_t OFF_H1R = OFF_PROG + 4096;
    constexpr size_t SZ_H1R = (size_t)4 * 4 * 2048 * 8;   // 256 KB
    constexpr size_t OFF_H0R = OFF_H1R + SZ_H1R;

    _Float16* wcat0 = (_Float16*)(ws + OFF_WCAT0);
    _Float16* wcat1 = (_Float16*)(ws + OFF_WCAT1);
    float* b0 = (float*)(ws + OFF_B0);
    float* b1 = (float*)(ws + OFF_B1);
    u32* prog = (u32*)(ws + OFF_PROG);
    u64* h1ring = (u64*)(ws + OFF_H1R);

    int R0 = 128;  // h0 ring slots; per group slot = 16 KB (tagged words)
    while (OFF_H0R + (size_t)4 * R0 * 2048 * 8 > ws_size && R0 > 16) R0 >>= 1;
    u64* h0ring = (u64*)(ws + OFF_H0R);

    // zero prog + both rings every launch (kills stale-tag acceptance across
    // graph replays)
    hipMemsetAsync(ws + OFF_PROG, 0,
                   (OFF_H0R - OFF_PROG) + (size_t)4 * R0 * 2048 * 8, stream);
    prep_weights<<<256, 256, 0, stream>>>(Wih0, Whh0, bih0, bhh0, Wih1, Whh1, bih1, bhh1,
                                          wcat0, wcat1, b0, b1);
    lstm_scan<<<32, 512, 0, stream>>>(x, h0, c0, wcat0, wcat1, b0, b1, Wfc, bfc,
                                      h0ring, h1ring, prog, out, R0);
}